// Round 4
// baseline (16.322 us; speedup 1.0000x reference)
//
#include <hip/hip_runtime.h>
#include <math.h>

// Problem constants (match reference).
constexpr int Bn = 1024;   // batch
constexpr int Fn = 512;    // features
constexpr int Kn = 16;     // factor dim
constexpr int CSTRIDE = 520;  // swizzled W^T row stride

// p2[b] = sum_{k,q} xs * ( sum_u xq[u]*wt[u]*vpre[u] + Tq_k(q+1)*Wrsum + lw )
// Thread t = 32k+q owns consumer (k,q) and row f=t.
//   wt[u]   = W[16q+u][k]    (via one swizzled LDS transpose per block)
//   vpre[u] = prefix of own W row (in-place, frees the row registers)
//   G       = sum_u xq[u]*wt[u];  Tq = 32-lane suffix scan of G over q
// VGPR-squeezed to <=64 (wt transient, dots fused) so 8 waves/SIMD ->
// 4 blocks/CU -> all 1024 blocks resident in ONE dispatch round.
// x loads issued first so cold-HBM latency hides under the W/LDS phase.
__global__ __launch_bounds__(512, 8) void fm_kernel(
    const float* __restrict__ x,      // (B,F)
    const float* __restrict__ W,      // (F,K)
    const float* __restrict__ lin_w,  // (1,F)
    const float* __restrict__ lin_b,  // (1,)
    float* __restrict__ out)          // (B,1)
{
    const int t = threadIdx.x;   // == row f this thread owns
    const int k = t >> 5;        // column this thread consumes
    const int q = t & 31;        // coarse 16-row block index
    const int b = blockIdx.x;

    __shared__ float WT[Kn * CSTRIDE];  // WT[k*CSTRIDE + swz(f)] = W[f][k]
    __shared__ float red[8];

    // ---- issue ALL x-side loads first (independent of W phase) ----
    const float* xb = x + (size_t)b * Fn;
    const float4* xq4 = reinterpret_cast<const float4*>(xb + 16 * q);
    const float4 c0 = xq4[0], c1 = xq4[1], c2 = xq4[2], c3 = xq4[3];
    const float xs = xb[t];
    const float lw = lin_w[t];

    // ---- W row (coalesced 64B/thread) -> swizzled LDS transpose ----
    const float4* Wrow4 = reinterpret_cast<const float4*>(W + t * Kn);
    const float4 a0 = Wrow4[0], a1 = Wrow4[1], a2 = Wrow4[2], a3 = Wrow4[3];
    float v[16] = {a0.x, a0.y, a0.z, a0.w, a1.x, a1.y, a1.z, a1.w,
                   a2.x, a2.y, a2.z, a2.w, a3.x, a3.y, a3.z, a3.w};

    const int fs = t ^ (t >> 5);  // <=2 lanes/bank per write = free (m136)
    #pragma unroll
    for (int kk = 0; kk < Kn; ++kk)
        WT[kk * CSTRIDE + fs] = v[kk];

    // Own-row prefix sums IN PLACE (row registers become vpre).
    #pragma unroll
    for (int u = 1; u < 16; ++u) v[u] += v[u - 1];
    const float Wrsum = v[15];

    __syncthreads();

    // Fused transpose-read + both dots: wt is a transient, never an array.
    // swz(16q+u) = 16q + (u ^ (q>>1)); conflict-free across the 32 q's.
    const float xq[16] = {c0.x, c0.y, c0.z, c0.w, c1.x, c1.y, c1.z, c1.w,
                          c2.x, c2.y, c2.z, c2.w, c3.x, c3.y, c3.z, c3.w};
    const int rbase = k * CSTRIDE + 16 * q;
    const int cxor = q >> 1;
    float G = 0.f, acc2 = 0.f;
    #pragma unroll
    for (int u = 0; u < 16; ++u) {
        const float wt = WT[rbase + (u ^ cxor)];
        const float m = xq[u] * wt;
        G += m;
        acc2 = fmaf(m, v[u], acc2);
    }

    // 32-lane inclusive suffix scan over q -> Tq_k(q+1).
    float incl = G;
    #pragma unroll
    for (int d = 1; d < 32; d <<= 1) {
        const float o = __shfl_down(incl, d, 32);
        if (q + d < 32) incl += o;
    }
    const float Tq = incl - G;

    float part = xs * (acc2 + Tq * Wrsum + lw);

    // Wave butterfly, one partial per wave.
    #pragma unroll
    for (int d = 32; d >= 1; d >>= 1)
        part += __shfl_xor(part, d);
    if ((t & 63) == 0) red[t >> 6] = part;

    __syncthreads();

    if (t == 0) {
        float tot = red[0] + red[1] + red[2] + red[3]
                  + red[4] + red[5] + red[6] + red[7];
        tot += lin_b[0];
        out[b] = 1.0f / (1.0f + expf(-tot));
    }
}

extern "C" void kernel_launch(void* const* d_in, const int* in_sizes, int n_in,
                              void* d_out, int out_size, void* d_ws, size_t ws_size,
                              hipStream_t stream) {
    const float* x     = (const float*)d_in[0];
    const float* W     = (const float*)d_in[1];
    const float* lin_w = (const float*)d_in[2];
    const float* lin_b = (const float*)d_in[3];
    float* out = (float*)d_out;

    hipLaunchKernelGGL(fm_kernel, dim3(Bn), dim3(512), 0, stream,
                       x, W, lin_w, lin_b, out);
}

// Round 5
// 10.058 us; speedup vs baseline: 1.6228x; 1.6228x over previous
//
#include <hip/hip_runtime.h>
#include <math.h>

// Problem constants (match reference).
constexpr int Bn = 1024;   // batch
constexpr int Fn = 512;    // features
constexpr int Kn = 16;     // factor dim
constexpr int CSTRIDE = 520;  // swizzled W^T row stride

// p2[b] = sum_{k,q} xs * ( sum_u xq[u]*wt[u]*vpre[u] + Tq_k(q+1)*Wrsum + lw )
// 256 threads/block, each owns TWO consumers (k1,q) and (k1+8,q) -> they share
// xq[16] (same q), halving x-register cost per consumer. Rows f1=t, f2=t+256.
// VGPR ~80 < 128 cap (launch_bounds(256,4): no spill -- R4's mistake was
// forcing 64 and spilling to scratch). LDS 33.3KB -> 4 blocks/CU -> all 1024
// blocks resident in ONE round (the residency experiment R4 failed to run).
__global__ __launch_bounds__(256, 4) void fm_kernel(
    const float* __restrict__ x,      // (B,F)
    const float* __restrict__ W,      // (F,K)
    const float* __restrict__ lin_w,  // (1,F)
    const float* __restrict__ lin_b,  // (1,)
    float* __restrict__ out)          // (B,1)
{
    const int t  = threadIdx.x;  // 0..255
    const int q  = t & 31;       // coarse 16-row block index (shared by both consumers)
    const int k1 = t >> 5;       // first consumer column (0..7); second is k1+8
    const int b  = blockIdx.x;

    __shared__ float WT[Kn * CSTRIDE];  // WT[k*CSTRIDE + swz(f)] = W[f][k]
    __shared__ float red[4];

    const float* xb = x + (size_t)b * Fn;

    // ---- x-side loads first: HBM latency hides under the W/LDS phase ----
    const float4* xq4 = reinterpret_cast<const float4*>(xb + 16 * q);
    const float4 c0 = xq4[0], c1 = xq4[1], c2 = xq4[2], c3 = xq4[3];
    const float xs1 = xb[t],       xs2 = xb[t + 256];
    const float lw1 = lin_w[t],    lw2 = lin_w[t + 256];

    // ---- two W rows (coalesced 64B) -> swizzled LDS transpose ----
    const float4* Wr1 = reinterpret_cast<const float4*>(W + t * Kn);
    const float4* Wr2 = reinterpret_cast<const float4*>(W + (t + 256) * Kn);
    const float4 a0 = Wr1[0], a1 = Wr1[1], a2 = Wr1[2], a3 = Wr1[3];
    const float4 e0 = Wr2[0], e1 = Wr2[1], e2 = Wr2[2], e3 = Wr2[3];
    float v1[16] = {a0.x,a0.y,a0.z,a0.w, a1.x,a1.y,a1.z,a1.w,
                    a2.x,a2.y,a2.z,a2.w, a3.x,a3.y,a3.z,a3.w};
    float v2[16] = {e0.x,e0.y,e0.z,e0.w, e1.x,e1.y,e1.z,e1.w,
                    e2.x,e2.y,e2.z,e2.w, e3.x,e3.y,e3.z,e3.w};

    const int f2 = t + 256;
    const int s1 = t  ^ (t  >> 5);   // write swizzle: <=2 lanes/bank = free
    const int s2 = f2 ^ (f2 >> 5);
    #pragma unroll
    for (int kk = 0; kk < Kn; ++kk) {
        WT[kk * CSTRIDE + s1] = v1[kk];
        WT[kk * CSTRIDE + s2] = v2[kk];
    }

    // Own-row prefix sums in place (rows become vpre).
    #pragma unroll
    for (int u = 1; u < 16; ++u) { v1[u] += v1[u-1]; v2[u] += v2[u-1]; }
    const float Ws1 = v1[15], Ws2 = v2[15];

    __syncthreads();

    // Fused transpose-read + dots for both consumers; wt values transient.
    // swz(16q+u) = 16q + (u ^ (q>>1)) -> conflict-free across the 32 q's.
    const float xq[16] = {c0.x,c0.y,c0.z,c0.w, c1.x,c1.y,c1.z,c1.w,
                          c2.x,c2.y,c2.z,c2.w, c3.x,c3.y,c3.z,c3.w};
    const int rb1 = k1 * CSTRIDE + 16 * q;
    const int rb2 = rb1 + 8 * CSTRIDE;
    const int cx  = q >> 1;
    float G1 = 0.f, G2 = 0.f, A1 = 0.f, A2 = 0.f;
    #pragma unroll
    for (int u = 0; u < 16; ++u) {
        const int o = u ^ cx;
        const float w1v = WT[rb1 + o];
        const float w2v = WT[rb2 + o];
        const float m1 = xq[u] * w1v;
        const float m2 = xq[u] * w2v;
        G1 += m1; A1 = fmaf(m1, v1[u], A1);
        G2 += m2; A2 = fmaf(m2, v2[u], A2);
    }

    // 32-lane inclusive suffix scans over q (independent -> ILP).
    float i1 = G1, i2 = G2;
    #pragma unroll
    for (int d = 1; d < 32; d <<= 1) {
        const float o1 = __shfl_down(i1, d, 32);
        const float o2 = __shfl_down(i2, d, 32);
        if (q + d < 32) { i1 += o1; i2 += o2; }
    }
    const float Tq1 = i1 - G1, Tq2 = i2 - G2;

    float part = xs1 * (A1 + Tq1 * Ws1 + lw1)
               + xs2 * (A2 + Tq2 * Ws2 + lw2);

    // Wave butterfly; 4 waves -> 4 partials.
    #pragma unroll
    for (int d = 32; d >= 1; d >>= 1)
        part += __shfl_xor(part, d);
    if ((t & 63) == 0) red[t >> 6] = part;

    __syncthreads();

    if (t == 0) {
        const float tot = red[0] + red[1] + red[2] + red[3] + lin_b[0];
        out[b] = 1.0f / (1.0f + expf(-tot));
    }
}

extern "C" void kernel_launch(void* const* d_in, const int* in_sizes, int n_in,
                              void* d_out, int out_size, void* d_ws, size_t ws_size,
                              hipStream_t stream) {
    const float* x     = (const float*)d_in[0];
    const float* W     = (const float*)d_in[1];
    const float* lin_w = (const float*)d_in[2];
    const float* lin_b = (const float*)d_in[3];
    float* out = (float*)d_out;

    hipLaunchKernelGGL(fm_kernel, dim3(Bn), dim3(256), 0, stream,
                       x, W, lin_w, lin_b, out);
}